// Round 5
// baseline (236.632 us; speedup 1.0000x reference)
//
#include <hip/hip_runtime.h>
#include <math.h>

#define B 8
#define N 2048
#define D 3072
#define GRID 512
#define NPB (N / GRID)            // 4 training rows per block in P1
#define NCHUNK 64
#define CHUNK (N / NCHUNK)        // 32
#define NSTRIPE 24                // d-stripes of 128 floats (lane owns float2)
#define NTASK (NSTRIPE * NCHUNK)  // 1536 = 3 * GRID
#define P4_BLOCKS ((B * D) / 256) // 96

// ---- device helpers ----------------------------------------------------

struct Scalars {
    float state_scale;  // sqrt(1 + var_tilde)
    float inv_2vt;      // 1 / (2 * var_tilde)
    float alpha;
    float inv_sigma;
};

__device__ inline Scalars compute_scalars(const float* __restrict__ ng) {
    float gamma = ng[0] * 25.0f - 15.0f;
    float var_tilde = expf(-gamma);
    float variance = 1.0f / (1.0f + expf(gamma));   // sigmoid(-gamma)
    Scalars s;
    s.state_scale = sqrtf(1.0f + var_tilde);
    s.inv_2vt     = 0.5f / var_tilde;
    s.alpha       = sqrtf(1.0f - variance);
    s.inv_sigma   = 1.0f / sqrtf(variance);
    return s;
}

// ---- grid barrier: sense-reversal, device-scope atomics -----------------
// bar[0]=count, bar[1]=sense. All blocks co-resident (512 = 2/CU by
// __launch_bounds__(256,2)). Reset each call by k_init.

__device__ inline void grid_barrier(int* __restrict__ bar) {
    __syncthreads();
    if (threadIdx.x == 0) {
        __threadfence();  // publish this block's prior global writes
        int my = __hip_atomic_load(&bar[1], __ATOMIC_RELAXED,
                                   __HIP_MEMORY_SCOPE_AGENT);
        int old = __hip_atomic_fetch_add(&bar[0], 1, __ATOMIC_ACQ_REL,
                                         __HIP_MEMORY_SCOPE_AGENT);
        if (old == GRID - 1) {
            __hip_atomic_store(&bar[0], 0, __ATOMIC_RELAXED,
                               __HIP_MEMORY_SCOPE_AGENT);
            __hip_atomic_store(&bar[1], my ^ 1, __ATOMIC_RELEASE,
                               __HIP_MEMORY_SCOPE_AGENT);
        } else {
            while (__hip_atomic_load(&bar[1], __ATOMIC_ACQUIRE,
                                     __HIP_MEMORY_SCOPE_AGENT) == my) {
                __builtin_amdgcn_s_sleep(2);
            }
        }
        __threadfence();  // acquire side: make others' writes visible
    }
    __syncthreads();
}

__global__ void k_init(int* __restrict__ bar) {
    if (threadIdx.x == 0) { bar[0] = 0; bar[1] = 0; }
}

// ---- fused kernel -------------------------------------------------------
// P1 sse -> P2 softmax -> P3 chunk partials -> P4 reduce+eps

__global__ __launch_bounds__(256, 2) void k_fused(
        const float* __restrict__ in, const float* __restrict__ ng,
        const float* __restrict__ mask, const float* __restrict__ train,
        float* __restrict__ sse, float* __restrict__ probT,
        float* __restrict__ partials, float* __restrict__ out,
        int* __restrict__ bar) {
    const int tid = threadIdx.x;
    const int bid = blockIdx.x;
    const Scalars sc = compute_scalars(ng);

    // ---------------- P1: sse[b][n] -------------------------------------
    {
        const int n0 = bid * NPB;

        float4 sm[3][B];   // pre-scaled, pre-masked input slice (registers)
        float4 m4[3];
#pragma unroll
        for (int k = 0; k < 3; ++k) {
            const int d = (tid + k * 256) * 4;
            m4[k] = *(const float4*)(mask + d);
#pragma unroll
            for (int b = 0; b < B; ++b) {
                const float4 s = *(const float4*)(in + b * D + d);
                sm[k][b].x = s.x * sc.state_scale * m4[k].x;
                sm[k][b].y = s.y * sc.state_scale * m4[k].y;
                sm[k][b].z = s.z * sc.state_scale * m4[k].z;
                sm[k][b].w = s.w * sc.state_scale * m4[k].w;
            }
        }

        __shared__ float red[NPB][4][B];
        const int wave = tid >> 6, lane = tid & 63;

#pragma unroll
        for (int j = 0; j < NPB; ++j) {
            const float* trow = train + (size_t)(n0 + j) * D;
            double acc[B];
#pragma unroll
            for (int b = 0; b < B; ++b) acc[b] = 0.0;

#pragma unroll
            for (int k = 0; k < 3; ++k) {
                const int d = (tid + k * 256) * 4;
                const float4 t = *(const float4*)(trow + d);
                float4 tm;
                tm.x = t.x * m4[k].x;
                tm.y = t.y * m4[k].y;
                tm.z = t.z * m4[k].z;
                tm.w = t.w * m4[k].w;
#pragma unroll
                for (int b = 0; b < B; ++b) {
                    float dx = sm[k][b].x - tm.x;
                    float dy = sm[k][b].y - tm.y;
                    float dz = sm[k][b].z - tm.z;
                    float dw = sm[k][b].w - tm.w;
                    float s4 = fmaf(dx, dx, fmaf(dy, dy, fmaf(dz, dz, dw * dw)));
                    acc[b] += (double)s4;   // 3 f64 adds per b total
                }
            }

#pragma unroll
            for (int b = 0; b < B; ++b) {
                float f = (float)acc[b];
                for (int off = 32; off; off >>= 1)
                    f += __shfl_down(f, off);
                if (lane == 0) red[j][wave][b] = f;
            }
        }
        __syncthreads();
        if (tid < NPB * B) {
            const int j = tid >> 3, b = tid & 7;
            sse[b * N + (n0 + j)] =
                red[j][0][b] + red[j][1][b] + red[j][2][b] + red[j][3][b];
        }
    }
    grid_barrier(bar);

    // ---------------- P2: softmax over n (blocks 0..7) ------------------
    if (bid < B) {
        const float* row = sse + bid * N;
        float v[N / 256];
#pragma unroll
        for (int k = 0; k < N / 256; ++k)
            v[k] = -row[tid + k * 256] * sc.inv_2vt;

        float mx = v[0];
#pragma unroll
        for (int k = 1; k < N / 256; ++k) mx = fmaxf(mx, v[k]);
        for (int off = 32; off; off >>= 1)
            mx = fmaxf(mx, __shfl_xor(mx, off));
        __shared__ float smx[4];
        if ((tid & 63) == 0) smx[tid >> 6] = mx;
        __syncthreads();
        mx = fmaxf(fmaxf(smx[0], smx[1]), fmaxf(smx[2], smx[3]));

        float e[N / 256];
        float sum = 0.0f;
#pragma unroll
        for (int k = 0; k < N / 256; ++k) {
            e[k] = expf(v[k] - mx);
            sum += e[k];
        }
        for (int off = 32; off; off >>= 1)
            sum += __shfl_xor(sum, off);
        __shared__ float ssum[4];
        if ((tid & 63) == 0) ssum[tid >> 6] = sum;
        __syncthreads();
        const float inv = 1.0f / (ssum[0] + ssum[1] + ssum[2] + ssum[3]);

#pragma unroll
        for (int k = 0; k < N / 256; ++k)
            probT[(tid + k * 256) * B + bid] = e[k] * inv;
    }
    grid_barrier(bar);

    // ---------------- P3: chunk partials --------------------------------
    // 3 wave-tasks per block (waves 0..2); lane owns a float2 of d.
    {
        const int wave = tid >> 6, lane = tid & 63;
        if (wave < 3) {
            const int task = bid + wave * GRID;    // 0..1535
            const int s = task % NSTRIPE;
            const int c = task / NSTRIPE;
            const int d = s * 128 + lane * 2;

            float2 acc[B];
#pragma unroll
            for (int b = 0; b < B; ++b) acc[b] = make_float2(0.f, 0.f);

            const int nbase = c * CHUNK;
#pragma unroll 8
            for (int i = 0; i < CHUNK; ++i) {
                const int n = nbase + i;
                const float2 t  = *(const float2*)(train + (size_t)n * D + d);
                const float4 p0 = *(const float4*)(probT + n * B);
                const float4 p1 = *(const float4*)(probT + n * B + 4);
                acc[0].x = fmaf(p0.x, t.x, acc[0].x); acc[0].y = fmaf(p0.x, t.y, acc[0].y);
                acc[1].x = fmaf(p0.y, t.x, acc[1].x); acc[1].y = fmaf(p0.y, t.y, acc[1].y);
                acc[2].x = fmaf(p0.z, t.x, acc[2].x); acc[2].y = fmaf(p0.z, t.y, acc[2].y);
                acc[3].x = fmaf(p0.w, t.x, acc[3].x); acc[3].y = fmaf(p0.w, t.y, acc[3].y);
                acc[4].x = fmaf(p1.x, t.x, acc[4].x); acc[4].y = fmaf(p1.x, t.y, acc[4].y);
                acc[5].x = fmaf(p1.y, t.x, acc[5].x); acc[5].y = fmaf(p1.y, t.y, acc[5].y);
                acc[6].x = fmaf(p1.z, t.x, acc[6].x); acc[6].y = fmaf(p1.z, t.y, acc[6].y);
                acc[7].x = fmaf(p1.w, t.x, acc[7].x); acc[7].y = fmaf(p1.w, t.y, acc[7].y);
            }
#pragma unroll
            for (int b = 0; b < B; ++b)
                *(float2*)(partials + ((size_t)(c * B + b)) * D + d) = acc[b];
        }
    }
    grid_barrier(bar);

    // ---------------- P4: reduce + eps (blocks 0..95) -------------------
    if (bid < P4_BLOCKS) {
        const int i = bid * 256 + tid;
        const int b = i / D;
        const int d = i - b * D;
        float s = 0.0f;
#pragma unroll 16
        for (int c = 0; c < NCHUNK; ++c)
            s += partials[((size_t)(c * B + b)) * D + d];
        out[i] = (in[i] - sc.alpha * s) * sc.inv_sigma * mask[d];
    }
}

// ---- launch --------------------------------------------------------------

extern "C" void kernel_launch(void* const* d_in, const int* in_sizes, int n_in,
                              void* d_out, int out_size, void* d_ws, size_t ws_size,
                              hipStream_t stream) {
    const float* in    = (const float*)d_in[0];   // [8,3,32,32]
    const float* ng    = (const float*)d_in[1];   // [1]
    const float* mask  = (const float*)d_in[2];   // [3,32,32]
    const float* train = (const float*)d_in[3];   // [2048,3,32,32]
    float* out = (float*)d_out;

    float* ws       = (float*)d_ws;
    float* sse      = ws;                        // B*N floats
    float* probT    = ws + B * N;                // N*B floats
    float* partials = ws + 2 * B * N;            // NCHUNK*B*D floats (6.3 MB)
    // barrier state: 4 KB past partials so streaming writes never share a
    // cacheline with the device-scope atomics (cross-XCD writeback hazard)
    int* bar = (int*)(ws + 2 * B * N + (size_t)NCHUNK * B * D + 1024);

    k_init<<<1, 64, 0, stream>>>(bar);
    k_fused<<<GRID, 256, 0, stream>>>(in, ng, mask, train,
                                      sse, probT, partials, out, bar);
}

// Round 6
// 173.446 us; speedup vs baseline: 1.3643x; 1.3643x over previous
//
#include <hip/hip_runtime.h>
#include <math.h>

#define B 8
#define N 2048
#define D 3072
#define GRID 512
#define NPB (N / GRID)            // 4 training rows per block in P1
#define NCHUNK 64
#define CHUNK (N / NCHUNK)        // 32
#define NSTRIPE 24                // d-stripes of 128 floats (lane owns float2)
#define NTASK (NSTRIPE * NCHUNK)  // 1536 = 3 * GRID
#define P4_BLOCKS ((B * D) / 256) // 96

#define BAR_STRIDE 32             // 128 B between barrier words
#define BAR_INTS (10 * BAR_STRIDE)

// ---- device helpers ----------------------------------------------------

struct Scalars {
    float state_scale;  // sqrt(1 + var_tilde)
    float inv_2vt;      // 1 / (2 * var_tilde)
    float alpha;
    float inv_sigma;
};

__device__ inline Scalars compute_scalars(const float* __restrict__ ng) {
    float gamma = ng[0] * 25.0f - 15.0f;
    float var_tilde = expf(-gamma);
    float variance = 1.0f / (1.0f + expf(gamma));   // sigmoid(-gamma)
    Scalars s;
    s.state_scale = sqrtf(1.0f + var_tilde);
    s.inv_2vt     = 0.5f / var_tilde;
    s.alpha       = sqrtf(1.0f - variance);
    s.inv_sigma   = 1.0f / sqrtf(variance);
    return s;
}

// ---- grid barrier: hierarchical, monotonic epochs, padded lines ---------
// layout: sub[g] @ g*32 (g=0..7, 64 blocks each), master @ 8*32,
// sense @ 9*32. Counters never reset during a call (epoch-monotonic);
// k_init zeroes them every call. Spinners read ONLY the sense line.

__device__ inline void grid_barrier(int* __restrict__ bar, int epoch) {
    __syncthreads();
    if (threadIdx.x == 0) {
        int* sub    = bar + (blockIdx.x & 7) * BAR_STRIDE;
        int* master = bar + 8 * BAR_STRIDE;
        int* sense  = bar + 9 * BAR_STRIDE;
        __threadfence();  // publish this block's prior global writes
        int old = __hip_atomic_fetch_add(sub, 1, __ATOMIC_ACQ_REL,
                                         __HIP_MEMORY_SCOPE_AGENT);
        if ((old & 63) == 63) {                       // group's last arrival
            int om = __hip_atomic_fetch_add(master, 1, __ATOMIC_ACQ_REL,
                                            __HIP_MEMORY_SCOPE_AGENT);
            if ((om & 7) == 7)                        // grid's last group
                __hip_atomic_store(sense, epoch, __ATOMIC_RELEASE,
                                   __HIP_MEMORY_SCOPE_AGENT);
        }
        while (__hip_atomic_load(sense, __ATOMIC_ACQUIRE,
                                 __HIP_MEMORY_SCOPE_AGENT) < epoch) {
            __builtin_amdgcn_s_sleep(16);
        }
        __threadfence();  // make others' writes visible
    }
    __syncthreads();
}

__global__ void k_init(int* __restrict__ bar) {
    for (int i = threadIdx.x; i < BAR_INTS; i += 256) bar[i] = 0;
}

// ---- fused kernel -------------------------------------------------------
// P1 sse -> P2 softmax -> P3 chunk partials -> P4 reduce+eps

__global__ __launch_bounds__(256, 2) void k_fused(
        const float* __restrict__ in, const float* __restrict__ ng,
        const float* __restrict__ mask, const float* __restrict__ train,
        float* __restrict__ sse, float* __restrict__ probT,
        float* __restrict__ partials, float* __restrict__ out,
        int* __restrict__ bar) {
    const int tid = threadIdx.x;
    const int bid = blockIdx.x;
    const Scalars sc = compute_scalars(ng);

    // ---------------- P1: sse[b][n] -------------------------------------
    {
        const int n0 = bid * NPB;

        float4 sm[3][B];   // pre-scaled, pre-masked input slice (registers)
        float4 m4[3];
#pragma unroll
        for (int k = 0; k < 3; ++k) {
            const int d = (tid + k * 256) * 4;
            m4[k] = *(const float4*)(mask + d);
#pragma unroll
            for (int b = 0; b < B; ++b) {
                const float4 s = *(const float4*)(in + b * D + d);
                sm[k][b].x = s.x * sc.state_scale * m4[k].x;
                sm[k][b].y = s.y * sc.state_scale * m4[k].y;
                sm[k][b].z = s.z * sc.state_scale * m4[k].z;
                sm[k][b].w = s.w * sc.state_scale * m4[k].w;
            }
        }

        __shared__ float red[NPB][4][B];
        const int wave = tid >> 6, lane = tid & 63;

#pragma unroll
        for (int j = 0; j < NPB; ++j) {
            const float* trow = train + (size_t)(n0 + j) * D;
            double acc[B];
#pragma unroll
            for (int b = 0; b < B; ++b) acc[b] = 0.0;

#pragma unroll
            for (int k = 0; k < 3; ++k) {
                const int d = (tid + k * 256) * 4;
                const float4 t = *(const float4*)(trow + d);
                float4 tm;
                tm.x = t.x * m4[k].x;
                tm.y = t.y * m4[k].y;
                tm.z = t.z * m4[k].z;
                tm.w = t.w * m4[k].w;
#pragma unroll
                for (int b = 0; b < B; ++b) {
                    float dx = sm[k][b].x - tm.x;
                    float dy = sm[k][b].y - tm.y;
                    float dz = sm[k][b].z - tm.z;
                    float dw = sm[k][b].w - tm.w;
                    float s4 = fmaf(dx, dx, fmaf(dy, dy, fmaf(dz, dz, dw * dw)));
                    acc[b] += (double)s4;   // 3 f64 adds per b total
                }
            }

#pragma unroll
            for (int b = 0; b < B; ++b) {
                float f = (float)acc[b];
                for (int off = 32; off; off >>= 1)
                    f += __shfl_down(f, off);
                if (lane == 0) red[j][wave][b] = f;
            }
        }
        __syncthreads();
        if (tid < NPB * B) {
            const int j = tid >> 3, b = tid & 7;
            sse[b * N + (n0 + j)] =
                red[j][0][b] + red[j][1][b] + red[j][2][b] + red[j][3][b];
        }
    }
    grid_barrier(bar, 1);

    // ---------------- P2: softmax over n (blocks 0..7) ------------------
    if (bid < B) {
        const float* row = sse + bid * N;
        float v[N / 256];
#pragma unroll
        for (int k = 0; k < N / 256; ++k)
            v[k] = -row[tid + k * 256] * sc.inv_2vt;

        float mx = v[0];
#pragma unroll
        for (int k = 1; k < N / 256; ++k) mx = fmaxf(mx, v[k]);
        for (int off = 32; off; off >>= 1)
            mx = fmaxf(mx, __shfl_xor(mx, off));
        __shared__ float smx[4];
        if ((tid & 63) == 0) smx[tid >> 6] = mx;
        __syncthreads();
        mx = fmaxf(fmaxf(smx[0], smx[1]), fmaxf(smx[2], smx[3]));

        float e[N / 256];
        float sum = 0.0f;
#pragma unroll
        for (int k = 0; k < N / 256; ++k) {
            e[k] = expf(v[k] - mx);
            sum += e[k];
        }
        for (int off = 32; off; off >>= 1)
            sum += __shfl_xor(sum, off);
        __shared__ float ssum[4];
        if ((tid & 63) == 0) ssum[tid >> 6] = sum;
        __syncthreads();
        const float inv = 1.0f / (ssum[0] + ssum[1] + ssum[2] + ssum[3]);

#pragma unroll
        for (int k = 0; k < N / 256; ++k)
            probT[(tid + k * 256) * B + bid] = e[k] * inv;
    }
    grid_barrier(bar, 2);

    // ---------------- P3: chunk partials --------------------------------
    // 3 wave-tasks per block (waves 0..2); lane owns a float2 of d.
    {
        const int wave = tid >> 6, lane = tid & 63;
        if (wave < 3) {
            const int task = bid + wave * GRID;    // 0..1535
            const int s = task % NSTRIPE;
            const int c = task / NSTRIPE;
            const int d = s * 128 + lane * 2;

            float2 acc[B];
#pragma unroll
            for (int b = 0; b < B; ++b) acc[b] = make_float2(0.f, 0.f);

            const int nbase = c * CHUNK;
#pragma unroll 8
            for (int i = 0; i < CHUNK; ++i) {
                const int n = nbase + i;
                const float2 t  = *(const float2*)(train + (size_t)n * D + d);
                const float4 p0 = *(const float4*)(probT + n * B);
                const float4 p1 = *(const float4*)(probT + n * B + 4);
                acc[0].x = fmaf(p0.x, t.x, acc[0].x); acc[0].y = fmaf(p0.x, t.y, acc[0].y);
                acc[1].x = fmaf(p0.y, t.x, acc[1].x); acc[1].y = fmaf(p0.y, t.y, acc[1].y);
                acc[2].x = fmaf(p0.z, t.x, acc[2].x); acc[2].y = fmaf(p0.z, t.y, acc[2].y);
                acc[3].x = fmaf(p0.w, t.x, acc[3].x); acc[3].y = fmaf(p0.w, t.y, acc[3].y);
                acc[4].x = fmaf(p1.x, t.x, acc[4].x); acc[4].y = fmaf(p1.x, t.y, acc[4].y);
                acc[5].x = fmaf(p1.y, t.x, acc[5].x); acc[5].y = fmaf(p1.y, t.y, acc[5].y);
                acc[6].x = fmaf(p1.z, t.x, acc[6].x); acc[6].y = fmaf(p1.z, t.y, acc[6].y);
                acc[7].x = fmaf(p1.w, t.x, acc[7].x); acc[7].y = fmaf(p1.w, t.y, acc[7].y);
            }
#pragma unroll
            for (int b = 0; b < B; ++b)
                *(float2*)(partials + ((size_t)(c * B + b)) * D + d) = acc[b];
        }
    }
    grid_barrier(bar, 3);

    // ---------------- P4: reduce + eps (blocks 0..95) -------------------
    if (bid < P4_BLOCKS) {
        const int i = bid * 256 + tid;
        const int b = i / D;
        const int d = i - b * D;
        float s = 0.0f;
#pragma unroll 16
        for (int c = 0; c < NCHUNK; ++c)
            s += partials[((size_t)(c * B + b)) * D + d];
        out[i] = (in[i] - sc.alpha * s) * sc.inv_sigma * mask[d];
    }
}

// ---- launch --------------------------------------------------------------

extern "C" void kernel_launch(void* const* d_in, const int* in_sizes, int n_in,
                              void* d_out, int out_size, void* d_ws, size_t ws_size,
                              hipStream_t stream) {
    const float* in    = (const float*)d_in[0];   // [8,3,32,32]
    const float* ng    = (const float*)d_in[1];   // [1]
    const float* mask  = (const float*)d_in[2];   // [3,32,32]
    const float* train = (const float*)d_in[3];   // [2048,3,32,32]
    float* out = (float*)d_out;

    float* ws       = (float*)d_ws;
    float* sse      = ws;                        // B*N floats
    float* probT    = ws + B * N;                // N*B floats
    float* partials = ws + 2 * B * N;            // NCHUNK*B*D floats (6.3 MB)
    // barrier state: 4 KB past partials, padded lines (see grid_barrier)
    int* bar = (int*)(ws + 2 * B * N + (size_t)NCHUNK * B * D + 1024);

    k_init<<<1, 256, 0, stream>>>(bar);
    k_fused<<<GRID, 256, 0, stream>>>(in, ng, mask, train,
                                      sse, probT, partials, out, bar);
}

// Round 7
// 68.117 us; speedup vs baseline: 3.4739x; 2.5463x over previous
//
#include <hip/hip_runtime.h>
#include <math.h>

#define B 8
#define N 2048
#define D 3072
#define GRID 512
#define NPB (N / GRID)            // 4 training rows per block in P1
#define NCHUNK 64
#define CHUNK (N / NCHUNK)        // 32
#define NSTRIPE 24                // d-stripes of 128 floats (lane owns float2)
#define NTASK (NSTRIPE * NCHUNK)  // 1536 = 3 * GRID
#define P4_BLOCKS ((B * D) / 256) // 96

#define BAR_STRIDE 32             // 128 B between barrier words
#define BAR_INTS (10 * BAR_STRIDE)

// ---- device helpers ----------------------------------------------------

struct Scalars {
    float state_scale;  // sqrt(1 + var_tilde)
    float inv_2vt;      // 1 / (2 * var_tilde)
    float alpha;
    float inv_sigma;
};

__device__ inline Scalars compute_scalars(const float* __restrict__ ng) {
    float gamma = ng[0] * 25.0f - 15.0f;
    float var_tilde = expf(-gamma);
    float variance = 1.0f / (1.0f + expf(gamma));   // sigmoid(-gamma)
    Scalars s;
    s.state_scale = sqrtf(1.0f + var_tilde);
    s.inv_2vt     = 0.5f / var_tilde;
    s.alpha       = sqrtf(1.0f - variance);
    s.inv_sigma   = 1.0f / sqrtf(variance);
    return s;
}

// ---- grid barrier: relaxed atomics + ONE wb / ONE inv per block ---------
// Theory: agent-scope ACQUIRE ops invalidate the local XCD L2 (non-coherent
// L2s) -> acquire-per-poll was the round-5/6 disaster. Here: one release
// fence (L2 writeback) before arrival, relaxed RMWs (LLC-point, no cache
// maintenance), relaxed spin loads, one acquire fence (L2 inv) after exit.
// Counters are epoch-monotonic, zeroed each call by k_init.

__device__ inline void grid_barrier(int* __restrict__ bar, int epoch, bool wait) {
    __syncthreads();
    if (threadIdx.x == 0) {
        int* sub    = bar + (blockIdx.x & 7) * BAR_STRIDE;
        int* master = bar + 8 * BAR_STRIDE;
        int* sense  = bar + 9 * BAR_STRIDE;
        __builtin_amdgcn_fence(__ATOMIC_RELEASE, "agent");   // wb dirty L2, once
        int old = __hip_atomic_fetch_add(sub, 1, __ATOMIC_RELAXED,
                                         __HIP_MEMORY_SCOPE_AGENT);
        if ((old & 63) == 63) {                    // group's last arrival
            int om = __hip_atomic_fetch_add(master, 1, __ATOMIC_RELAXED,
                                            __HIP_MEMORY_SCOPE_AGENT);
            if ((om & 7) == 7)                     // grid's last group
                __hip_atomic_store(sense, epoch, __ATOMIC_RELAXED,
                                   __HIP_MEMORY_SCOPE_AGENT);
        }
        if (wait) {
            while (__hip_atomic_load(sense, __ATOMIC_RELAXED,
                                     __HIP_MEMORY_SCOPE_AGENT) < epoch) {
                __builtin_amdgcn_s_sleep(8);
            }
            __builtin_amdgcn_fence(__ATOMIC_ACQUIRE, "agent"); // inv L2, once
        }
    }
    __syncthreads();
}

__global__ void k_init(int* __restrict__ bar) {
    for (int i = threadIdx.x; i < BAR_INTS; i += 256) bar[i] = 0;
}

// ---- fused kernel -------------------------------------------------------
// P1 sse -> P2 softmax -> P3 chunk partials -> P4 reduce+eps

__global__ __launch_bounds__(256, 2) void k_fused(
        const float* __restrict__ in, const float* __restrict__ ng,
        const float* __restrict__ mask, const float* __restrict__ train,
        float* __restrict__ sse, float* __restrict__ probT,
        float* __restrict__ partials, float* __restrict__ out,
        int* __restrict__ bar) {
    const int tid = threadIdx.x;
    const int bid = blockIdx.x;
    const Scalars sc = compute_scalars(ng);

    // ---------------- P1: sse[b][n] -------------------------------------
    {
        const int n0 = bid * NPB;

        float4 sm[3][B];   // pre-scaled, pre-masked input slice (registers)
        float4 m4[3];
#pragma unroll
        for (int k = 0; k < 3; ++k) {
            const int d = (tid + k * 256) * 4;
            m4[k] = *(const float4*)(mask + d);
#pragma unroll
            for (int b = 0; b < B; ++b) {
                const float4 s = *(const float4*)(in + b * D + d);
                sm[k][b].x = s.x * sc.state_scale * m4[k].x;
                sm[k][b].y = s.y * sc.state_scale * m4[k].y;
                sm[k][b].z = s.z * sc.state_scale * m4[k].z;
                sm[k][b].w = s.w * sc.state_scale * m4[k].w;
            }
        }

        __shared__ float red[NPB][4][B];
        const int wave = tid >> 6, lane = tid & 63;

#pragma unroll
        for (int j = 0; j < NPB; ++j) {
            const float* trow = train + (size_t)(n0 + j) * D;
            double acc[B];
#pragma unroll
            for (int b = 0; b < B; ++b) acc[b] = 0.0;

#pragma unroll
            for (int k = 0; k < 3; ++k) {
                const int d = (tid + k * 256) * 4;
                const float4 t = *(const float4*)(trow + d);
                float4 tm;
                tm.x = t.x * m4[k].x;
                tm.y = t.y * m4[k].y;
                tm.z = t.z * m4[k].z;
                tm.w = t.w * m4[k].w;
#pragma unroll
                for (int b = 0; b < B; ++b) {
                    float dx = sm[k][b].x - tm.x;
                    float dy = sm[k][b].y - tm.y;
                    float dz = sm[k][b].z - tm.z;
                    float dw = sm[k][b].w - tm.w;
                    float s4 = fmaf(dx, dx, fmaf(dy, dy, fmaf(dz, dz, dw * dw)));
                    acc[b] += (double)s4;   // 3 f64 adds per b total
                }
            }

#pragma unroll
            for (int b = 0; b < B; ++b) {
                float f = (float)acc[b];
                for (int off = 32; off; off >>= 1)
                    f += __shfl_down(f, off);
                if (lane == 0) red[j][wave][b] = f;
            }
        }
        __syncthreads();
        if (tid < NPB * B) {
            const int j = tid >> 3, b = tid & 7;
            sse[b * N + (n0 + j)] =
                red[j][0][b] + red[j][1][b] + red[j][2][b] + red[j][3][b];
        }
    }
    grid_barrier(bar, 1, true);

    // ---------------- P2: softmax over n (blocks 0..7) ------------------
    if (bid < B) {
        const float* row = sse + bid * N;
        float v[N / 256];
#pragma unroll
        for (int k = 0; k < N / 256; ++k)
            v[k] = -row[tid + k * 256] * sc.inv_2vt;

        float mx = v[0];
#pragma unroll
        for (int k = 1; k < N / 256; ++k) mx = fmaxf(mx, v[k]);
        for (int off = 32; off; off >>= 1)
            mx = fmaxf(mx, __shfl_xor(mx, off));
        __shared__ float smx[4];
        if ((tid & 63) == 0) smx[tid >> 6] = mx;
        __syncthreads();
        mx = fmaxf(fmaxf(smx[0], smx[1]), fmaxf(smx[2], smx[3]));

        float e[N / 256];
        float sum = 0.0f;
#pragma unroll
        for (int k = 0; k < N / 256; ++k) {
            e[k] = expf(v[k] - mx);
            sum += e[k];
        }
        for (int off = 32; off; off >>= 1)
            sum += __shfl_xor(sum, off);
        __shared__ float ssum[4];
        if ((tid & 63) == 0) ssum[tid >> 6] = sum;
        __syncthreads();
        const float inv = 1.0f / (ssum[0] + ssum[1] + ssum[2] + ssum[3]);

#pragma unroll
        for (int k = 0; k < N / 256; ++k)
            probT[(tid + k * 256) * B + bid] = e[k] * inv;
    }
    grid_barrier(bar, 2, true);

    // ---------------- P3: chunk partials --------------------------------
    // 3 wave-tasks per block (waves 0..2); lane owns a float2 of d.
    {
        const int wave = tid >> 6, lane = tid & 63;
        if (wave < 3) {
            const int task = bid + wave * GRID;    // 0..1535
            const int s = task % NSTRIPE;
            const int c = task / NSTRIPE;
            const int d = s * 128 + lane * 2;

            float2 acc[B];
#pragma unroll
            for (int b = 0; b < B; ++b) acc[b] = make_float2(0.f, 0.f);

            const int nbase = c * CHUNK;
#pragma unroll 8
            for (int i = 0; i < CHUNK; ++i) {
                const int n = nbase + i;
                const float2 t  = *(const float2*)(train + (size_t)n * D + d);
                const float4 p0 = *(const float4*)(probT + n * B);
                const float4 p1 = *(const float4*)(probT + n * B + 4);
                acc[0].x = fmaf(p0.x, t.x, acc[0].x); acc[0].y = fmaf(p0.x, t.y, acc[0].y);
                acc[1].x = fmaf(p0.y, t.x, acc[1].x); acc[1].y = fmaf(p0.y, t.y, acc[1].y);
                acc[2].x = fmaf(p0.z, t.x, acc[2].x); acc[2].y = fmaf(p0.z, t.y, acc[2].y);
                acc[3].x = fmaf(p0.w, t.x, acc[3].x); acc[3].y = fmaf(p0.w, t.y, acc[3].y);
                acc[4].x = fmaf(p1.x, t.x, acc[4].x); acc[4].y = fmaf(p1.x, t.y, acc[4].y);
                acc[5].x = fmaf(p1.y, t.x, acc[5].x); acc[5].y = fmaf(p1.y, t.y, acc[5].y);
                acc[6].x = fmaf(p1.z, t.x, acc[6].x); acc[6].y = fmaf(p1.z, t.y, acc[6].y);
                acc[7].x = fmaf(p1.w, t.x, acc[7].x); acc[7].y = fmaf(p1.w, t.y, acc[7].y);
            }
#pragma unroll
            for (int b = 0; b < B; ++b)
                *(float2*)(partials + ((size_t)(c * B + b)) * D + d) = acc[b];
        }
    }
    // only P4 blocks need to observe completion; others arrive and exit
    grid_barrier(bar, 3, bid < P4_BLOCKS);

    // ---------------- P4: reduce + eps (blocks 0..95) -------------------
    if (bid < P4_BLOCKS) {
        const int i = bid * 256 + tid;
        const int b = i / D;
        const int d = i - b * D;
        float s = 0.0f;
#pragma unroll 16
        for (int c = 0; c < NCHUNK; ++c)
            s += partials[((size_t)(c * B + b)) * D + d];
        out[i] = (in[i] - sc.alpha * s) * sc.inv_sigma * mask[d];
    }
}

// ---- launch --------------------------------------------------------------

extern "C" void kernel_launch(void* const* d_in, const int* in_sizes, int n_in,
                              void* d_out, int out_size, void* d_ws, size_t ws_size,
                              hipStream_t stream) {
    const float* in    = (const float*)d_in[0];   // [8,3,32,32]
    const float* ng    = (const float*)d_in[1];   // [1]
    const float* mask  = (const float*)d_in[2];   // [3,32,32]
    const float* train = (const float*)d_in[3];   // [2048,3,32,32]
    float* out = (float*)d_out;

    float* ws       = (float*)d_ws;
    float* sse      = ws;                        // B*N floats
    float* probT    = ws + B * N;                // N*B floats
    float* partials = ws + 2 * B * N;            // NCHUNK*B*D floats (6.3 MB)
    // barrier state: 4 KB past partials, padded lines (see grid_barrier)
    int* bar = (int*)(ws + 2 * B * N + (size_t)NCHUNK * B * D + 1024);

    k_init<<<1, 256, 0, stream>>>(bar);
    k_fused<<<GRID, 256, 0, stream>>>(in, ng, mask, train,
                                      sse, probT, partials, out, bar);
}

// Round 8
// 55.003 us; speedup vs baseline: 4.3022x; 1.2384x over previous
//
#include <hip/hip_runtime.h>
#include <math.h>

#define B 8
#define N 2048
#define D 3072
#define GRID 512
#define NPB (N / GRID)            // 4 training rows per block in P1
#define NCHUNK 64
#define CHUNK (N / NCHUNK)        // 32
#define NSTRIPE 24                // d-stripes of 128 floats (lane owns 2 d's)
#define NTASK (NSTRIPE * NCHUNK)  // 1536 = 3 * GRID
#define P4_BLOCKS ((B * D) / 256) // 96

// flag regions (ints): A[512] P1-done, B2[64] P2-done (8 used), C[512] P3-done
#define FLAGS_INTS (512 + 64 + 512)

#define AL(p)    __hip_atomic_load((p), __ATOMIC_RELAXED, __HIP_MEMORY_SCOPE_AGENT)
#define AS(p, v) __hip_atomic_store((p), (v), __ATOMIC_RELAXED, __HIP_MEMORY_SCOPE_AGENT)

// ---- device helpers ----------------------------------------------------

struct Scalars {
    float state_scale;  // sqrt(1 + var_tilde)
    float inv_2vt;      // 1 / (2 * var_tilde)
    float alpha;
    float inv_sigma;
};

__device__ inline Scalars compute_scalars(const float* __restrict__ ng) {
    float gamma = ng[0] * 25.0f - 15.0f;
    float var_tilde = expf(-gamma);
    float variance = 1.0f / (1.0f + expf(gamma));   // sigmoid(-gamma)
    Scalars s;
    s.state_scale = sqrtf(1.0f + var_tilde);
    s.inv_2vt     = 0.5f / var_tilde;
    s.alpha       = sqrtf(1.0f - variance);
    s.inv_sigma   = 1.0f / sqrtf(variance);
    return s;
}

// signal: release fence (orders this block's sc1 data stores) + flag store.
// No RMW -> no serialization; wb finds no dirty L2 (ws writes are sc1).
__device__ inline void signal_flag(int* __restrict__ flag) {
    __syncthreads();
    if (threadIdx.x == 0) {
        __builtin_amdgcn_fence(__ATOMIC_RELEASE, "agent");
        AS(flag, 1);
    }
    __syncthreads();
}

__global__ void k_init(int* __restrict__ flags) {
    for (int i = threadIdx.x; i < FLAGS_INTS; i += 256) flags[i] = 0;
}

// ---- fused kernel -------------------------------------------------------
// P1 sse -> P2 softmax -> P3 chunk partials -> P4 reduce+eps
// Cross-block data (sse, probT, partials) via relaxed agent atomics (LLC);
// read-only inputs via normal cached loads (L2 stays warm, never inv'd).

__global__ __launch_bounds__(256, 2) void k_fused(
        const float* __restrict__ in, const float* __restrict__ ng,
        const float* __restrict__ mask, const float* __restrict__ train,
        float* __restrict__ sse, float* __restrict__ probT,
        float* __restrict__ partials, float* __restrict__ out,
        int* __restrict__ flags) {
    const int tid = threadIdx.x;
    const int bid = blockIdx.x;
    const Scalars sc = compute_scalars(ng);

    int* flagsA = flags;
    int* flagsB = flags + 512;
    int* flagsC = flags + 512 + 64;

    // ---------------- P1: sse[b][n] -------------------------------------
    {
        const int n0 = bid * NPB;

        float4 sm[3][B];   // pre-scaled, pre-masked input slice (registers)
        float4 m4[3];
#pragma unroll
        for (int k = 0; k < 3; ++k) {
            const int d = (tid + k * 256) * 4;
            m4[k] = *(const float4*)(mask + d);
#pragma unroll
            for (int b = 0; b < B; ++b) {
                const float4 s = *(const float4*)(in + b * D + d);
                sm[k][b].x = s.x * sc.state_scale * m4[k].x;
                sm[k][b].y = s.y * sc.state_scale * m4[k].y;
                sm[k][b].z = s.z * sc.state_scale * m4[k].z;
                sm[k][b].w = s.w * sc.state_scale * m4[k].w;
            }
        }

        __shared__ float red[NPB][4][B];
        const int wave = tid >> 6, lane = tid & 63;

#pragma unroll
        for (int j = 0; j < NPB; ++j) {
            const float* trow = train + (size_t)(n0 + j) * D;
            double acc[B];
#pragma unroll
            for (int b = 0; b < B; ++b) acc[b] = 0.0;

#pragma unroll
            for (int k = 0; k < 3; ++k) {
                const int d = (tid + k * 256) * 4;
                const float4 t = *(const float4*)(trow + d);
                float4 tm;
                tm.x = t.x * m4[k].x;
                tm.y = t.y * m4[k].y;
                tm.z = t.z * m4[k].z;
                tm.w = t.w * m4[k].w;
#pragma unroll
                for (int b = 0; b < B; ++b) {
                    float dx = sm[k][b].x - tm.x;
                    float dy = sm[k][b].y - tm.y;
                    float dz = sm[k][b].z - tm.z;
                    float dw = sm[k][b].w - tm.w;
                    float s4 = fmaf(dx, dx, fmaf(dy, dy, fmaf(dz, dz, dw * dw)));
                    acc[b] += (double)s4;   // 3 f64 adds per b total
                }
            }

#pragma unroll
            for (int b = 0; b < B; ++b) {
                float f = (float)acc[b];
                for (int off = 32; off; off >>= 1)
                    f += __shfl_down(f, off);
                if (lane == 0) red[j][wave][b] = f;
            }
        }
        __syncthreads();
        if (tid < NPB * B) {
            const int j = tid >> 3, b = tid & 7;
            AS(&sse[b * N + (n0 + j)],
               red[j][0][b] + red[j][1][b] + red[j][2][b] + red[j][3][b]);
        }
    }
    signal_flag(&flagsA[bid]);

    // ---------------- P2: softmax over n (blocks 0..7) ------------------
    if (bid < B) {
        // wait for all 512 P1 flags (parallel scan, load-only)
        for (int i = tid; i < GRID; i += 256)
            while (AL(&flagsA[i]) == 0) __builtin_amdgcn_s_sleep(2);
        __syncthreads();

        float v[N / 256];
#pragma unroll
        for (int k = 0; k < N / 256; ++k)
            v[k] = -AL(&sse[bid * N + tid + k * 256]) * sc.inv_2vt;

        float mx = v[0];
#pragma unroll
        for (int k = 1; k < N / 256; ++k) mx = fmaxf(mx, v[k]);
        for (int off = 32; off; off >>= 1)
            mx = fmaxf(mx, __shfl_xor(mx, off));
        __shared__ float smx[4];
        if ((tid & 63) == 0) smx[tid >> 6] = mx;
        __syncthreads();
        mx = fmaxf(fmaxf(smx[0], smx[1]), fmaxf(smx[2], smx[3]));

        float e[N / 256];
        float sum = 0.0f;
#pragma unroll
        for (int k = 0; k < N / 256; ++k) {
            e[k] = expf(v[k] - mx);
            sum += e[k];
        }
        for (int off = 32; off; off >>= 1)
            sum += __shfl_xor(sum, off);
        __shared__ float ssum[4];
        if ((tid & 63) == 0) ssum[tid >> 6] = sum;
        __syncthreads();
        const float inv = 1.0f / (ssum[0] + ssum[1] + ssum[2] + ssum[3]);

#pragma unroll
        for (int k = 0; k < N / 256; ++k)
            AS(&probT[(tid + k * 256) * B + bid], e[k] * inv);

        signal_flag(&flagsB[bid]);
    }

    // ---------------- wait: probT ready (8 flags, load-only) -------------
    if (tid < B)
        while (AL(&flagsB[tid]) == 0) __builtin_amdgcn_s_sleep(2);
    __syncthreads();

    // ---------------- P3: chunk partials --------------------------------
    // 3 wave-tasks per block (waves 0..2); lane owns 2 d's.
    {
        const int wave = tid >> 6, lane = tid & 63;
        if (wave < 3) {
            const int task = bid + wave * GRID;    // 0..1535
            const int s = task % NSTRIPE;
            const int c = task / NSTRIPE;
            const int d = s * 128 + lane * 2;

            float2 acc[B];
#pragma unroll
            for (int b = 0; b < B; ++b) acc[b] = make_float2(0.f, 0.f);

            const int nbase = c * CHUNK;
#pragma unroll 8
            for (int i = 0; i < CHUNK; ++i) {
                const int n = nbase + i;
                const float2 t = *(const float2*)(train + (size_t)n * D + d);
                float p[B];
#pragma unroll
                for (int b = 0; b < B; ++b) p[b] = AL(&probT[n * B + b]);
#pragma unroll
                for (int b = 0; b < B; ++b) {
                    acc[b].x = fmaf(p[b], t.x, acc[b].x);
                    acc[b].y = fmaf(p[b], t.y, acc[b].y);
                }
            }
#pragma unroll
            for (int b = 0; b < B; ++b) {
                AS(&partials[((size_t)(c * B + b)) * D + d],     acc[b].x);
                AS(&partials[((size_t)(c * B + b)) * D + d + 1], acc[b].y);
            }
        }
    }
    signal_flag(&flagsC[bid]);

    // ---------------- P4: reduce + eps (blocks 0..95) -------------------
    if (bid < P4_BLOCKS) {
        for (int i = tid; i < GRID; i += 256)
            while (AL(&flagsC[i]) == 0) __builtin_amdgcn_s_sleep(2);
        __syncthreads();

        const int i = bid * 256 + tid;
        const int b = i / D;
        const int d = i - b * D;
        float s = 0.0f;
#pragma unroll 16
        for (int c = 0; c < NCHUNK; ++c)
            s += AL(&partials[((size_t)(c * B + b)) * D + d]);
        out[i] = (in[i] - sc.alpha * s) * sc.inv_sigma * mask[d];
    }
}

// ---- launch --------------------------------------------------------------

extern "C" void kernel_launch(void* const* d_in, const int* in_sizes, int n_in,
                              void* d_out, int out_size, void* d_ws, size_t ws_size,
                              hipStream_t stream) {
    const float* in    = (const float*)d_in[0];   // [8,3,32,32]
    const float* ng    = (const float*)d_in[1];   // [1]
    const float* mask  = (const float*)d_in[2];   // [3,32,32]
    const float* train = (const float*)d_in[3];   // [2048,3,32,32]
    float* out = (float*)d_out;

    float* ws       = (float*)d_ws;
    float* sse      = ws;                        // B*N floats
    float* probT    = ws + B * N;                // N*B floats
    float* partials = ws + 2 * B * N;            // NCHUNK*B*D floats (6.3 MB)
    int*   flags    = (int*)(ws + 2 * B * N + (size_t)NCHUNK * B * D + 1024);

    k_init<<<1, 256, 0, stream>>>(flags);
    k_fused<<<GRID, 256, 0, stream>>>(in, ng, mask, train,
                                      sse, probT, partials, out, flags);
}